// Round 1
// baseline (537.416 us; speedup 1.0000x reference)
//
#include <hip/hip_runtime.h>

// WeightedLoss: loss_i = (target_i == 1) ? 1 - sigmoid(pred_i) : 0.1 ; out = mean(loss)
// 1 - sigmoid(x) = sigmoid(-x) = 1 / (1 + exp(x))
// Memory-bound: 512 MiB in / 4 B out. Strategy: float4/int4 grid-stride read,
// per-thread fp32 accumulate, wave-64 shuffle reduce, LDS across 4 waves,
// one atomicAdd per block of (block_sum * 1/N). 1/N = 2^-26 exact in fp32.

__global__ __launch_bounds__(256)
void wloss_kernel(const float* __restrict__ pred,
                  const int*   __restrict__ tgt,
                  float* __restrict__ out,
                  long long n, float inv_n) {
    const long long n4     = n >> 2;
    const long long tid    = (long long)blockIdx.x * blockDim.x + threadIdx.x;
    const long long stride = (long long)gridDim.x * blockDim.x;

    const float4* __restrict__ p4 = (const float4*)pred;
    const int4*   __restrict__ t4 = (const int4*)tgt;

    float acc = 0.0f;
    for (long long i = tid; i < n4; i += stride) {
        float4 p = p4[i];
        int4   t = t4[i];
        float l0 = (t.x == 1) ? 1.0f / (1.0f + __expf(p.x)) : 0.1f;
        float l1 = (t.y == 1) ? 1.0f / (1.0f + __expf(p.y)) : 0.1f;
        float l2 = (t.z == 1) ? 1.0f / (1.0f + __expf(p.z)) : 0.1f;
        float l3 = (t.w == 1) ? 1.0f / (1.0f + __expf(p.w)) : 0.1f;
        acc += (l0 + l1) + (l2 + l3);
    }

    // Scalar tail (n not divisible by 4) — block 0 only. N=2^26 here, so empty,
    // but keep it correct for any n.
    if (blockIdx.x == 0) {
        for (long long i = (n4 << 2) + threadIdx.x; i < n; i += blockDim.x) {
            acc += (tgt[i] == 1) ? 1.0f / (1.0f + __expf(pred[i])) : 0.1f;
        }
    }

    // Wave-64 shuffle reduction
    #pragma unroll
    for (int off = 32; off > 0; off >>= 1)
        acc += __shfl_down(acc, off, 64);

    // Cross-wave reduction (256 threads = 4 waves)
    __shared__ float smem[4];
    const int lane = threadIdx.x & 63;
    const int wave = threadIdx.x >> 6;
    if (lane == 0) smem[wave] = acc;
    __syncthreads();
    if (threadIdx.x == 0) {
        float bsum = (smem[0] + smem[1]) + (smem[2] + smem[3]);
        atomicAdd(out, bsum * inv_n);  // device-scope by default on CDNA
    }
}

extern "C" void kernel_launch(void* const* d_in, const int* in_sizes, int n_in,
                              void* d_out, int out_size, void* d_ws, size_t ws_size,
                              hipStream_t stream) {
    const float* pred = (const float*)d_in[0];
    const int*   tgt  = (const int*)d_in[1];
    float*       out  = (float*)d_out;

    const long long n = (long long)in_sizes[0];

    // d_out is poisoned (0xAA) before every launch; zero it with a capture-safe
    // async memset so the per-block atomicAdd accumulates from 0.
    hipMemsetAsync(out, 0, sizeof(float), stream);

    const int block = 256;
    const long long n4 = n >> 2;
    long long g = (n4 + block - 1) / block;
    if (g > 8192) g = 8192;
    if (g < 1)    g = 1;

    wloss_kernel<<<(int)g, block, 0, stream>>>(pred, tgt, out, n, 1.0f / (float)n);
}